// Round 14
// baseline (122.337 us; speedup 1.0000x reference)
//
#include <hip/hip_runtime.h>
#include <hip/hip_fp16.h>

// SelfAttention: B=8, C=64, N=4096, d_head=8.
// o[b,c,m] = gamma * sum_n h[b,c,n] * softmax_n(f[:,n].g[:,m]) + x[b,c,m]
// R14: attn S=8 key-splits (2048 blocks = 8/CU -> ~2x resident waves; attn is
// latency-bound: no pipe >60%) + revert ones-MFMA to scalar ls (R13 neutral,
// cost VGPR+MFMA pipe). 128-col sharing retained. Cascade S=8/4/2/1 by ws.

typedef _Float16 half8_t __attribute__((ext_vector_type(8)));
typedef _Float16 half4_t __attribute__((ext_vector_type(4)));
typedef _Float16 half2_t __attribute__((ext_vector_type(2)));
typedef __fp16  fp16x2  __attribute__((ext_vector_type(2)));
typedef float float4_t __attribute__((ext_vector_type(4)));

#define NTOK 4096
#define PRH 72   // LDS row stride in halves (144 B: b64 reads 2-way = free)
#define LOG2E 1.44269504088896340736f

#if __has_builtin(__builtin_amdgcn_exp2f)
__device__ __forceinline__ float fexp2(float x) { return __builtin_amdgcn_exp2f(x); }
#else
__device__ __forceinline__ float fexp2(float x) { return exp2f(x); }
#endif

__device__ __forceinline__ half2_t pkcvt(float a, float b) {
    fp16x2 v = __builtin_amdgcn_cvt_pkrtz(a, b);
    return __builtin_bit_cast(half2_t, v);
}

// ---------------- projection (MFMA) ------------------------------------------
// grid (128 token-tiles of 32, 8 b), block 320 = 5 waves = 5 out-row-groups.
// fTR records: [b][kt64*16+ml][q 0..3][t4][4] halves; q>=2 slots hold the
// K-pad constants ({1,0,0,0} row, zeros) so attn loads unconditionally.
__global__ __launch_bounds__(320) void proj_kernel(
    const float* __restrict__ x,
    const float* __restrict__ Wq, const float* __restrict__ bq,
    const float* __restrict__ Wk, const float* __restrict__ bk,
    const float* __restrict__ Wv, const float* __restrict__ bv,
    __half* __restrict__ fTR, __half* __restrict__ gT16, __half* __restrict__ hM)
{
    __shared__ __align__(16) _Float16 xh[32 * PRH];   // 4.6 KB
    const int t      = threadIdx.x;
    const int blk    = blockIdx.x;
    const int b      = blockIdx.y;
    const int n0     = blk * 32;
    const int kt64   = blk >> 1;
    const int t4base = (blk & 1) * 2;

    if (t < 256) {
#pragma unroll
        for (int i = 0; i < 2; i++) {
            const int idx = t + i * 256;
            const int c = idx >> 3, f4 = idx & 7;
            float4 v = *(const float4*)(x + (((size_t)(b * 64 + c)) << 12) + n0 + f4 * 4);
            const int cs = c ^ ((f4 & 3) << 4);
            xh[(f4 * 4 + 0) * PRH + cs] = (_Float16)v.x;
            xh[(f4 * 4 + 1) * PRH + cs] = (_Float16)v.y;
            xh[(f4 * 4 + 2) * PRH + cs] = (_Float16)v.z;
            xh[(f4 * 4 + 3) * PRH + cs] = (_Float16)v.w;
        }
    }

    const int w    = t >> 6;
    const int lane = t & 63;
    const int q    = lane >> 4;
    const int ml   = lane & 15;

    const float* wrow;
    if (w == 0) wrow = (ml < 8) ? (Wq + ml * 64) : (Wk + (ml - 8) * 64);
    else        wrow = Wv + ((w - 1) * 16 + ml) * 64;
    half4_t afr[4];
#pragma unroll
    for (int ks = 0; ks < 4; ks++) {
        float4 wv4 = *(const float4*)(wrow + ks * 16 + q * 4);
        afr[ks] = (half4_t){(_Float16)wv4.x, (_Float16)wv4.y,
                            (_Float16)wv4.z, (_Float16)wv4.w};
    }
    float4 bias4;
    if (w == 0) bias4 = (q < 2) ? *(const float4*)(bq + q * 4)
                                : *(const float4*)(bk + (q - 2) * 4);
    else        bias4 = *(const float4*)(bv + (w - 1) * 16 + q * 4);

    __syncthreads();

#pragma unroll
    for (int cg = 0; cg < 2; cg++) {
        const int tok  = cg * 16 + ml;
        const int swz  = (tok >> 2) & 3;
        float4_t acc = (float4_t){0.f, 0.f, 0.f, 0.f};
#pragma unroll
        for (int ks = 0; ks < 4; ks++) {
            half4_t bfr = *(const half4_t*)(&xh[tok * PRH + ((ks ^ swz) * 16 + q * 4)]);
            acc = __builtin_amdgcn_mfma_f32_16x16x16f16(afr[ks], bfr, acc, 0, 0, 0);
        }
        acc[0] += bias4.x; acc[1] += bias4.y; acc[2] += bias4.z; acc[3] += bias4.w;
        const int gtok = n0 + tok;
        const int t4   = t4base + cg;

        if (w == 0) {
            __half* rec = fTR + ((size_t)b << 16) + (size_t)(kt64 * 16 + ml) * 64;
            if (q < 2) {
                half4_t fv = {(_Float16)(acc[0] * LOG2E), (_Float16)(acc[1] * LOG2E),
                              (_Float16)(acc[2] * LOG2E), (_Float16)(acc[3] * LOG2E)};
                *(half4_t*)(rec + q * 16 + t4 * 4) = fv;
            } else {
                half4_t cv = (half4_t){};
                if (q == 2) cv[0] = (_Float16)1.0f;
                *(half4_t*)(rec + q * 16 + t4 * 4) = cv;
            }
            float gn2p = acc[0] * acc[0] + acc[1] * acc[1] +
                         acc[2] * acc[2] + acc[3] * acc[3];
            float gn2 = gn2p + __shfl_xor(gn2p, 16, 64);
            if (q >= 2) {
                half4_t gv = {(_Float16)acc[0], (_Float16)acc[1],
                              (_Float16)acc[2], (_Float16)acc[3]};
                __half* gp = gT16 + (size_t)((b << 12) + gtok) * 16;
                *(half4_t*)(gp + (q - 2) * 4) = gv;
                if (q == 2) {
                    const float M = (LOG2E * 4.6f) * __builtin_sqrtf(gn2) + 1.0f;
                    *(half4_t*)(gp + 8) = (half4_t){(_Float16)(-M), 0, 0, 0};
                } else {
                    *(half4_t*)(gp + 12) = (half4_t){};
                }
            }
        } else {
            const int ch = (w - 1) * 16 + q * 4;
#pragma unroll
            for (int r = 0; r < 4; r++)
                hM[(((size_t)b * 64 + ch + r) << 12) + gtok] = __float2half(acc[r]);
        }
    }
}

// ---------------- fused flash attention (key-split, shifted softmax) ---------
// grid (32 colblocks of 128, 8 b, S), block 256 = 4 waves x 32 cols (2 groups).
template<int NT>
__global__ __launch_bounds__(256) void attn_kernel(
    const __half* __restrict__ fTR, const __half* __restrict__ gT16,
    const __half* __restrict__ hM,
    __half* __restrict__ Pacc, float* __restrict__ Lsum)
{
    __shared__ __align__(16) _Float16 hl[2][64 * PRH];  // 2 x 9216 B
    const int tid   = threadIdx.x;
    const int w     = tid >> 6;
    const int lane  = tid & 63;
    const int q     = lane >> 4;
    const int ml    = lane & 15;
    const int b     = blockIdx.y;
    const int split = blockIdx.z;
    const int colA  = blockIdx.x * 128 + w * 16 + ml;
    const int colB  = colA + 64;

    half4_t gfA = *(const half4_t*)(gT16 + ((size_t)((b << 12) + colA)) * 16 + q * 4);
    half4_t gfB = *(const half4_t*)(gT16 + ((size_t)((b << 12) + colB)) * 16 + q * 4);

    float4_t accA[4], accB[4];
#pragma unroll
    for (int cg = 0; cg < 4; cg++) {
        accA[cg] = (float4_t){0.f, 0.f, 0.f, 0.f};
        accB[cg] = (float4_t){0.f, 0.f, 0.f, 0.f};
    }
    float lsA = 0.f, lsB = 0.f;

    const int kt0 = split * NT;
    const int c0  = tid >> 3;
    const int g0  = tid & 7;

    const __half* srow0 = hM + ((size_t)(b * 64 + c0) << 12) + kt0 * 64 + g0 * 8;
    const __half* srow1 = srow0 + ((size_t)32 << 12);
    const __half* fptr  = fTR + ((size_t)b << 16) + (size_t)(kt0 * 16 + ml) * 64 + q * 16;

    // ---- prologue: stage tile 0 + f record (2 x b128, unconditional) ----
    uint4 s0 = *(const uint4*)srow0;
    uint4 s1 = *(const uint4*)srow1;
    half8_t f01 = *(const half8_t*)fptr;
    half8_t f23 = *(const half8_t*)(fptr + 8);
    *(uint4*)(&hl[0][c0 * PRH + g0 * 8])        = s0;
    *(uint4*)(&hl[0][(c0 + 32) * PRH + g0 * 8]) = s1;
    __syncthreads();

#pragma unroll 1
    for (int kt = 0; kt < NT; kt++) {
        const _Float16* hbL = &hl[kt & 1][ml * PRH + q * 4];
        half4_t afn0 = __builtin_shufflevector(f01, f01, 0, 1, 2, 3);
        half4_t afn1 = __builtin_shufflevector(f01, f01, 4, 5, 6, 7);
        half4_t afn2 = __builtin_shufflevector(f23, f23, 0, 1, 2, 3);
        half4_t afn3 = __builtin_shufflevector(f23, f23, 4, 5, 6, 7);

        float4_t stA0 = __builtin_amdgcn_mfma_f32_16x16x16f16(
            afn0, gfA, (float4_t){0.f, 0.f, 0.f, 0.f}, 0, 0, 0);
        float4_t stA1 = __builtin_amdgcn_mfma_f32_16x16x16f16(
            afn1, gfA, (float4_t){0.f, 0.f, 0.f, 0.f}, 0, 0, 0);
        float4_t stA2 = __builtin_amdgcn_mfma_f32_16x16x16f16(
            afn2, gfA, (float4_t){0.f, 0.f, 0.f, 0.f}, 0, 0, 0);
        float4_t stA3 = __builtin_amdgcn_mfma_f32_16x16x16f16(
            afn3, gfA, (float4_t){0.f, 0.f, 0.f, 0.f}, 0, 0, 0);
        float4_t stB0 = __builtin_amdgcn_mfma_f32_16x16x16f16(
            afn0, gfB, (float4_t){0.f, 0.f, 0.f, 0.f}, 0, 0, 0);
        float4_t stB1 = __builtin_amdgcn_mfma_f32_16x16x16f16(
            afn1, gfB, (float4_t){0.f, 0.f, 0.f, 0.f}, 0, 0, 0);
        float4_t stB2 = __builtin_amdgcn_mfma_f32_16x16x16f16(
            afn2, gfB, (float4_t){0.f, 0.f, 0.f, 0.f}, 0, 0, 0);
        float4_t stB3 = __builtin_amdgcn_mfma_f32_16x16x16f16(
            afn3, gfB, (float4_t){0.f, 0.f, 0.f, 0.f}, 0, 0, 0);

        if (kt + 1 < NT) {
            f01 = *(const half8_t*)(fptr + 1024);
            f23 = *(const half8_t*)(fptr + 1032);
            s0 = *(const uint4*)(srow0 + 64);
            s1 = *(const uint4*)(srow1 + 64);
            fptr  += 1024;
            srow0 += 64;
            srow1 += 64;
        }

        {
            float pA0 = fexp2(stA0[0]), pA1 = fexp2(stA0[1]),
                  pA2 = fexp2(stA0[2]), pA3 = fexp2(stA0[3]);
            float pB0 = fexp2(stB0[0]), pB1 = fexp2(stB0[1]),
                  pB2 = fexp2(stB0[2]), pB3 = fexp2(stB0[3]);
            lsA += (pA0 + pA1) + (pA2 + pA3);
            lsB += (pB0 + pB1) + (pB2 + pB3);
            half2_t a_lo = pkcvt(pA0, pA1), a_hi = pkcvt(pA2, pA3);
            half2_t b_lo = pkcvt(pB0, pB1), b_hi = pkcvt(pB2, pB3);
            half4_t pfA = {a_lo[0], a_lo[1], a_hi[0], a_hi[1]};
            half4_t pfB = {b_lo[0], b_lo[1], b_hi[0], b_hi[1]};
#pragma unroll
            for (int cg = 0; cg < 4; cg++) {
                half4_t ah = *(const half4_t*)(hbL + cg * (16 * PRH) + 0 * 16);
                accA[cg] = __builtin_amdgcn_mfma_f32_16x16x16f16(ah, pfA, accA[cg], 0, 0, 0);
                accB[cg] = __builtin_amdgcn_mfma_f32_16x16x16f16(ah, pfB, accB[cg], 0, 0, 0);
            }
        }
        {
            float pA0 = fexp2(stA1[0]), pA1 = fexp2(stA1[1]),
                  pA2 = fexp2(stA1[2]), pA3 = fexp2(stA1[3]);
            float pB0 = fexp2(stB1[0]), pB1 = fexp2(stB1[1]),
                  pB2 = fexp2(stB1[2]), pB3 = fexp2(stB1[3]);
            lsA += (pA0 + pA1) + (pA2 + pA3);
            lsB += (pB0 + pB1) + (pB2 + pB3);
            half2_t a_lo = pkcvt(pA0, pA1), a_hi = pkcvt(pA2, pA3);
            half2_t b_lo = pkcvt(pB0, pB1), b_hi = pkcvt(pB2, pB3);
            half4_t pfA = {a_lo[0], a_lo[1], a_hi[0], a_hi[1]};
            half4_t pfB = {b_lo[0], b_lo[1], b_hi[0], b_hi[1]};
#pragma unroll
            for (int cg = 0; cg < 4; cg++) {
                half4_t ah = *(const half4_t*)(hbL + cg * (16 * PRH) + 1 * 16);
                accA[cg] = __builtin_amdgcn_mfma_f32_16x16x16f16(ah, pfA, accA[cg], 0, 0, 0);
                accB[cg] = __builtin_amdgcn_mfma_f32_16x16x16f16(ah, pfB, accB[cg], 0, 0, 0);
            }
        }
        {
            float pA0 = fexp2(stA2[0]), pA1 = fexp2(stA2[1]),
                  pA2 = fexp2(stA2[2]), pA3 = fexp2(stA2[3]);
            float pB0 = fexp2(stB2[0]), pB1 = fexp2(stB2[1]),
                  pB2 = fexp2(stB2[2]), pB3 = fexp2(stB2[3]);
            lsA += (pA0 + pA1) + (pA2 + pA3);
            lsB += (pB0 + pB1) + (pB2 + pB3);
            half2_t a_lo = pkcvt(pA0, pA1), a_hi = pkcvt(pA2, pA3);
            half2_t b_lo = pkcvt(pB0, pB1), b_hi = pkcvt(pB2, pB3);
            half4_t pfA = {a_lo[0], a_lo[1], a_hi[0], a_hi[1]};
            half4_t pfB = {b_lo[0], b_lo[1], b_hi[0], b_hi[1]};
#pragma unroll
            for (int cg = 0; cg < 4; cg++) {
                half4_t ah = *(const half4_t*)(hbL + cg * (16 * PRH) + 2 * 16);
                accA[cg] = __builtin_amdgcn_mfma_f32_16x16x16f16(ah, pfA, accA[cg], 0, 0, 0);
                accB[cg] = __builtin_amdgcn_mfma_f32_16x16x16f16(ah, pfB, accB[cg], 0, 0, 0);
            }
        }
        {
            float pA0 = fexp2(stA3[0]), pA1 = fexp2(stA3[1]),
                  pA2 = fexp2(stA3[2]), pA3 = fexp2(stA3[3]);
            float pB0 = fexp2(stB3[0]), pB1 = fexp2(stB3[1]),
                  pB2 = fexp2(stB3[2]), pB3 = fexp2(stB3[3]);
            lsA += (pA0 + pA1) + (pA2 + pA3);
            lsB += (pB0 + pB1) + (pB2 + pB3);
            half2_t a_lo = pkcvt(pA0, pA1), a_hi = pkcvt(pA2, pA3);
            half2_t b_lo = pkcvt(pB0, pB1), b_hi = pkcvt(pB2, pB3);
            half4_t pfA = {a_lo[0], a_lo[1], a_hi[0], a_hi[1]};
            half4_t pfB = {b_lo[0], b_lo[1], b_hi[0], b_hi[1]};
#pragma unroll
            for (int cg = 0; cg < 4; cg++) {
                half4_t ah = *(const half4_t*)(hbL + cg * (16 * PRH) + 3 * 16);
                accA[cg] = __builtin_amdgcn_mfma_f32_16x16x16f16(ah, pfA, accA[cg], 0, 0, 0);
                accB[cg] = __builtin_amdgcn_mfma_f32_16x16x16f16(ah, pfB, accB[cg], 0, 0, 0);
            }
        }

        if (kt + 1 < NT) {
            _Float16* hn = &hl[(kt + 1) & 1][0];
            *(uint4*)(&hn[c0 * PRH + g0 * 8])        = s0;
            *(uint4*)(&hn[(c0 + 32) * PRH + g0 * 8]) = s1;
        }
        __syncthreads();
    }

    // ---- deferred l reductions over the column's 4 lanes ----
    lsA += __shfl_xor(lsA, 16, 64);
    lsA += __shfl_xor(lsA, 32, 64);
    lsB += __shfl_xor(lsB, 16, 64);
    lsB += __shfl_xor(lsB, 32, 64);

    // ---- store UNNORMALIZED partials (shift is split-invariant) ----
    __half* pa = Pacc + (((size_t)(split * 8 + b) * 64) << 12);
#pragma unroll
    for (int cg = 0; cg < 4; cg++)
#pragma unroll
        for (int r = 0; r < 4; r++) {
            int ch = cg * 16 + q * 4 + r;
            pa[((size_t)ch << 12) + colA] = __float2half(accA[cg][r]);
            pa[((size_t)ch << 12) + colB] = __float2half(accB[cg][r]);
        }
    if (q == 0) {
        Lsum[((size_t)(split * 8 + b) << 12) + colA] = lsA;
        Lsum[((size_t)(split * 8 + b) << 12) + colB] = lsB;
    }
}

// ---------------- merge ------------------------------------------------------
// grid (64 col-tiles, 8 b, 4 ch-groups of 16), block 256 = 16 ch x 16 col-quads.
template<int S>
__global__ __launch_bounds__(256) void merge_kernel(
    const __half* __restrict__ Pacc, const float* __restrict__ Lsum,
    const float* __restrict__ x, const float* __restrict__ gammap,
    float* __restrict__ out)
{
    __shared__ float invL[64];
    const int tid  = threadIdx.x;
    const int c4   = tid & 15;
    const int chh  = tid >> 4;
    const int b    = blockIdx.y;
    const int col0 = blockIdx.x * 64;
    const int ch   = blockIdx.z * 16 + chh;

    if (tid < 64) {
        float L = 0.f;
#pragma unroll
        for (int s = 0; s < S; s++)
            L += Lsum[((size_t)(s * 8 + b) << 12) + col0 + tid];
        invL[tid] = gammap[0] / L;
    }
    __syncthreads();

    const int cc = c4 * 4;
    const size_t base = (((size_t)b * 64 + ch) << 12) + col0 + cc;
    float4 xv = *(const float4*)(x + base);
    float o0 = 0.f, o1 = 0.f, o2 = 0.f, o3 = 0.f;
#pragma unroll
    for (int s = 0; s < S; s++) {
        half4_t pv = *(const half4_t*)(Pacc +
            (((size_t)(s * 8 + b) * 64 + ch) << 12) + col0 + cc);
        o0 += (float)pv[0];
        o1 += (float)pv[1];
        o2 += (float)pv[2];
        o3 += (float)pv[3];
    }
    float4 ov;
    ov.x = o0 * invL[cc]     + xv.x;
    ov.y = o1 * invL[cc + 1] + xv.y;
    ov.z = o2 * invL[cc + 2] + xv.z;
    ov.w = o3 * invL[cc + 3] + xv.w;
    *(float4*)(out + base) = ov;
}

extern "C" void kernel_launch(void* const* d_in, const int* in_sizes, int n_in,
                              void* d_out, int out_size, void* d_ws, size_t ws_size,
                              hipStream_t stream) {
    const float* x     = (const float*)d_in[0];
    const float* Wq    = (const float*)d_in[1];
    const float* bq    = (const float*)d_in[2];
    const float* Wk    = (const float*)d_in[3];
    const float* bk    = (const float*)d_in[4];
    const float* Wv    = (const float*)d_in[5];
    const float* bv    = (const float*)d_in[6];
    const float* gamma = (const float*)d_in[7];
    float* out = (float*)d_out;

    const size_t fr_bytes  = (size_t)8 * 65536 * 2;             // 1 MB (fTR)
    const size_t g_bytes   = (size_t)8 * NTOK * 16 * 2;         // 1 MB
    const size_t hM_bytes  = (size_t)8 * 64 * NTOK * 2;         // 4 MB
    const size_t pa_split  = (size_t)8 * 64 * NTOK * 2;         // 4 MB per split
    const size_t l_split   = (size_t)8 * NTOK * sizeof(float);  // 128 KB per split
    const size_t base_need = fr_bytes + g_bytes + hM_bytes;

    int S = 1;
    if (ws_size >= base_need + 8 * (pa_split + l_split)) S = 8;
    else if (ws_size >= base_need + 4 * (pa_split + l_split)) S = 4;
    else if (ws_size >= base_need + 2 * (pa_split + l_split)) S = 2;

    char* p = (char*)d_ws;
    __half* fTR  = (__half*)p;  p += fr_bytes;
    __half* gT16 = (__half*)p;  p += g_bytes;
    __half* hM   = (__half*)p;  p += hM_bytes;
    __half* Pacc = (__half*)p;  p += (size_t)S * pa_split;
    float*  Lsum = (float*)p;

    proj_kernel<<<dim3(128, 8), 320, 0, stream>>>(x, Wq, bq, Wk, bk, Wv, bv,
                                                  fTR, gT16, hM);
    if (S == 8) {
        attn_kernel<8><<<dim3(32, 8, 8), 256, 0, stream>>>(fTR, gT16, hM, Pacc, Lsum);
        merge_kernel<8><<<dim3(64, 8, 4), 256, 0, stream>>>(Pacc, Lsum, x, gamma, out);
    } else if (S == 4) {
        attn_kernel<16><<<dim3(32, 8, 4), 256, 0, stream>>>(fTR, gT16, hM, Pacc, Lsum);
        merge_kernel<4><<<dim3(64, 8, 4), 256, 0, stream>>>(Pacc, Lsum, x, gamma, out);
    } else if (S == 2) {
        attn_kernel<32><<<dim3(32, 8, 2), 256, 0, stream>>>(fTR, gT16, hM, Pacc, Lsum);
        merge_kernel<2><<<dim3(64, 8, 4), 256, 0, stream>>>(Pacc, Lsum, x, gamma, out);
    } else {
        attn_kernel<64><<<dim3(32, 8, 1), 256, 0, stream>>>(fTR, gT16, hM, Pacc, Lsum);
        merge_kernel<1><<<dim3(64, 8, 4), 256, 0, stream>>>(Pacc, Lsum, x, gamma, out);
    }
}